// Round 7
// baseline (194.918 us; speedup 1.0000x reference)
//
#include <hip/hip_runtime.h>
#include <hip/hip_cooperative_groups.h>
#include <math.h>

namespace cg = cooperative_groups;

#define NTOK 2048
#define DMODEL 512
#define NH 8
#define HD 64
#define NF 128
#define QKV_LD 1536
#define CHUNK 64
#define NCHUNK 32
#define EPS_C 1e-8f

typedef __bf16 bf16x8 __attribute__((ext_vector_type(8)));
typedef float f32x4 __attribute__((ext_vector_type(4)));

__device__ inline unsigned short f2bf(float f) {
  union { float f; unsigned u; } v; v.f = f;
  unsigned r = v.u + 0x7FFF + ((v.u >> 16) & 1);   // RNE
  return (unsigned short)(r >> 16);
}

// Packed fragment layout PK(M,K) for MFMA operand (A: [m][k]; B: [n][k]):
//   unit(m,k)  = ((m>>4)*(K>>5) + (k>>5))*64 + (m&15) + ((k>>3)&3)*16
//   ushort idx = unit*8 + (k&7)

// ============ phase 0: pack inputs -> packed bf16 (+ V'' ones tile) ============
// 1184 job-blocks: [0,512) x | [512,896) W_qkv | [896,1024) W_out |
// [1024,1056) proj | [1056,1184) vT ones.
__device__ void ph_pack(
    const float* x, const float* W_qkv, const float* W_out, const float* proj,
    unsigned short* xpk, unsigned short* wqkvpk, unsigned short* woutpk,
    unsigned short* projpk, unsigned short* vT_pk)
{
  for (int v = blockIdx.x; v < 1184; v += gridDim.x) {
    unsigned short o[8];
    if (v < 512) {
      const int tid = v * 256 + threadIdx.x;            // < 131072
      const int lane = tid & 63, blk = tid >> 6;
      const int bk = blk & 15, bm = blk >> 4;
      const int m = bm * 16 + (lane & 15), k = bk * 32 + (lane >> 4) * 8;
      const float4 v0 = *(const float4*)&x[(size_t)m * 512 + k];
      const float4 v1 = *(const float4*)&x[(size_t)m * 512 + k + 4];
      o[0] = f2bf(v0.x); o[1] = f2bf(v0.y); o[2] = f2bf(v0.z); o[3] = f2bf(v0.w);
      o[4] = f2bf(v1.x); o[5] = f2bf(v1.y); o[6] = f2bf(v1.z); o[7] = f2bf(v1.w);
      *(ushort4*)&xpk[(size_t)tid * 8]     = *(ushort4*)&o[0];
      *(ushort4*)&xpk[(size_t)tid * 8 + 4] = *(ushort4*)&o[4];
    } else if (v < 896) {
      const int tid = (v - 512) * 256 + threadIdx.x;    // < 98304
      const int lane = tid & 63, blk = tid >> 6;
      const int bk = blk & 15, bn = blk >> 4;
      const int n = bn * 16 + (lane & 15), k = bk * 32 + (lane >> 4) * 8;
#pragma unroll
      for (int e = 0; e < 8; ++e) o[e] = f2bf(W_qkv[(size_t)(k + e) * QKV_LD + n]);
      *(ushort4*)&wqkvpk[(size_t)tid * 8]     = *(ushort4*)&o[0];
      *(ushort4*)&wqkvpk[(size_t)tid * 8 + 4] = *(ushort4*)&o[4];
    } else if (v < 1024) {
      const int tid = (v - 896) * 256 + threadIdx.x;    // < 32768
      const int lane = tid & 63, blk = tid >> 6;
      const int bk = blk & 15, bn = blk >> 4;
      const int n = bn * 16 + (lane & 15), k = bk * 32 + (lane >> 4) * 8;
#pragma unroll
      for (int e = 0; e < 8; ++e) o[e] = f2bf(W_out[(size_t)(k + e) * DMODEL + n]);
      *(ushort4*)&woutpk[(size_t)tid * 8]     = *(ushort4*)&o[0];
      *(ushort4*)&woutpk[(size_t)tid * 8 + 4] = *(ushort4*)&o[4];
    } else if (v < 1056) {
      const int tid = (v - 1024) * 256 + threadIdx.x;   // < 8192
      const int lane = tid & 63, blk = (tid >> 6) & 15, h = tid >> 10;
      const int bk = blk & 1, bn = blk >> 1;
      const int n = bn * 16 + (lane & 15), k = bk * 32 + (lane >> 4) * 8;
#pragma unroll
      for (int e = 0; e < 8; ++e) o[e] = f2bf(proj[(size_t)h * HD * NF + (size_t)(k + e) * NF + n]);
      *(ushort4*)&projpk[(size_t)tid * 8]     = *(ushort4*)&o[0];
      *(ushort4*)&projpk[(size_t)tid * 8 + 4] = *(ushort4*)&o[4];
    } else {
      const int tid = (v - 1056) * 256 + threadIdx.x;   // < 32768
      const int hc = tid >> 7, kt = (tid >> 6) & 1, lane = tid & 63;
      const unsigned short val = ((lane & 15) == 0) ? (unsigned short)0x3F80 : (unsigned short)0;
      const size_t u = (size_t)hc * 640 + (4 * 2 + kt) * 64 + lane;
#pragma unroll
      for (int e = 0; e < 8; ++e) o[e] = val;
      *(ushort4*)&vT_pk[u * 8]     = *(ushort4*)&o[0];
      *(ushort4*)&vT_pk[u * 8 + 4] = *(ushort4*)&o[4];
    }
  }
}

// ============ phase 1: fused qkv GEMM + proj + elu+1 ============
// 768 jobs: bx = j%24 (0-7 Q, 8-15 K, 16-23 V), c = j/24 chunk.
__device__ void ph_qkvproj(
    const unsigned short* Apk, const unsigned short* Bpk,
    const unsigned short* projpk, unsigned short* q_pk, unsigned short* k_pk,
    unsigned short* kT_pk, unsigned short* vT_pk)
{
  __shared__ unsigned short QK[4096];   // PK(64,64), 8 KB
  const int lane = threadIdx.x & 63, w = threadIdx.x >> 6;
  const int wr = w >> 1, wc = w & 1;
  const int r16 = lane & 15, kg = lane >> 4;
  for (int j = blockIdx.x; j < 768; j += gridDim.x) {
    const int bx = j % 24, c = j / 24;
    const int m0 = c * 64 + wr * 32;
    const int n0 = bx * 64 + wc * 32;
    const unsigned short* a0 = Apk + ((size_t)(m0 >> 4) * 16 * 64 + lane) * 8;
    const unsigned short* a1 = a0 + (size_t)16 * 512;
    const unsigned short* b0 = Bpk + ((size_t)(n0 >> 4) * 16 * 64 + lane) * 8;
    const unsigned short* b1 = b0 + (size_t)16 * 512;
    f32x4 acc00 = {0.f, 0.f, 0.f, 0.f}, acc01 = acc00, acc10 = acc00, acc11 = acc00;
#pragma unroll 4
    for (int s = 0; s < 16; ++s) {
      const bf16x8 af0 = *(const bf16x8*)(a0 + (size_t)s * 512);
      const bf16x8 af1 = *(const bf16x8*)(a1 + (size_t)s * 512);
      const bf16x8 bv0 = *(const bf16x8*)(b0 + (size_t)s * 512);
      const bf16x8 bv1 = *(const bf16x8*)(b1 + (size_t)s * 512);
      acc00 = __builtin_amdgcn_mfma_f32_16x16x32_bf16(af0, bv0, acc00, 0, 0, 0);
      acc01 = __builtin_amdgcn_mfma_f32_16x16x32_bf16(af0, bv1, acc01, 0, 0, 0);
      acc10 = __builtin_amdgcn_mfma_f32_16x16x32_bf16(af1, bv0, acc10, 0, 0, 0);
      acc11 = __builtin_amdgcn_mfma_f32_16x16x32_bf16(af1, bv1, acc11, 0, 0, 0);
    }
    if (bx < 16) {
      const int src = bx >> 3, h = bx & 7;
      // qkv tile -> LDS PK(64,64)
#pragma unroll
      for (int mb = 0; mb < 2; ++mb) {
#pragma unroll
        for (int nb = 0; nb < 2; ++nb) {
          const f32x4 a = mb == 0 ? (nb == 0 ? acc00 : acc01) : (nb == 0 ? acc10 : acc11);
          const size_t u = ((size_t)(wr * 2 + mb) * 2 + wc) * 64 +
                           (nb * 2 + (r16 >> 3)) * 16 + kg * 4;
          const int elem = r16 & 7;
#pragma unroll
          for (int r = 0; r < 4; ++r)
            QK[(u + r) * 8 + elem] = f2bf(a[r]);
        }
      }
      __syncthreads();
      // proj GEMM 64x128xK=64 + elu+1
      const unsigned short* bbase = projpk + (size_t)h * 8192 + (size_t)lane * 8;
      f32x4 p[2][4] = {};
#pragma unroll
      for (int s = 0; s < 2; ++s) {
#pragma unroll
        for (int mb = 0; mb < 2; ++mb) {
          const bf16x8 af = *(const bf16x8*)&QK[((((size_t)(wr * 2 + mb)) * 2 + s) * 64 + lane) * 8];
#pragma unroll
          for (int nb = 0; nb < 4; ++nb) {
            const bf16x8 bv = *(const bf16x8*)(bbase + (size_t)((wc * 4 + nb) * 2 + s) * 512);
            p[mb][nb] = __builtin_amdgcn_mfma_f32_16x16x32_bf16(af, bv, p[mb][nb], 0, 0, 0);
          }
        }
      }
      unsigned short* dst = (src ? k_pk : q_pk) + (size_t)h * 262144;
#pragma unroll
      for (int mb = 0; mb < 2; ++mb) {
#pragma unroll
        for (int nb = 0; nb < 4; ++nb) {
          unsigned short vb[4];
#pragma unroll
          for (int r = 0; r < 4; ++r) {
            const float vv = p[mb][nb][r];
            vb[r] = f2bf(vv > 0.f ? vv + 1.f : expf(vv));
          }
          const size_t base = ((size_t)(c * 4 + wr * 2 + mb) * 4 + wc * 2 + (nb >> 1)) * 64 +
                              ((nb & 1) * 2 + (r16 >> 3)) * 16;
          const int elem = r16 & 7;
#pragma unroll
          for (int r = 0; r < 4; ++r)
            dst[(base + kg * 4 + r) * 8 + elem] = vb[r];
          if (src == 1) {
            const size_t u = (size_t)(h * 32 + c) * 1024 +
                ((size_t)(wc * 4 + nb) * 2 + wr) * 64 + r16 + (mb * 2 + (kg >> 1)) * 16;
            *(ushort4*)&kT_pk[u * 8 + (kg & 1) * 4] = *(ushort4*)&vb[0];
          }
        }
      }
      __syncthreads();   // protect QK LDS reuse by next grid-stride iteration
    } else {
      // V -> vT_pk PK(80,64) per (h,c), transposed
      const int h = bx - 16;
#pragma unroll
      for (int mb = 0; mb < 2; ++mb) {
#pragma unroll
        for (int nb = 0; nb < 2; ++nb) {
          const f32x4 a = mb == 0 ? (nb == 0 ? acc00 : acc01) : (nb == 0 ? acc10 : acc11);
          const int vc = wc * 32 + nb * 16 + r16;
          const size_t u = (size_t)(h * 32 + c) * 640 +
              ((size_t)(vc >> 4) * 2 + wr) * 64 + (vc & 15) + (mb * 2 + (kg >> 1)) * 16;
          ushort4 rr;
          rr.x = f2bf(a[0]); rr.y = f2bf(a[1]); rr.z = f2bf(a[2]); rr.w = f2bf(a[3]);
          *(ushort4*)&vT_pk[u * 8 + (kg & 1) * 4] = rr;
        }
      }
    }
  }
}

// ============ phase 2: fused chunk-sums + exclusive scan ============
// 40 jobs: vt = j%5, h = j/5. MFMA accumulator IS the running prefix.
__device__ void ph_scan(
    const unsigned short* kT_pk, const unsigned short* vT_pk,
    unsigned short* kvpre_pk)
{
  const int lane = threadIdx.x & 63, w = threadIdx.x >> 6;
  const int r16 = lane & 15, kg = lane >> 4;
  for (int j = blockIdx.x; j < 40; j += gridDim.x) {
    const int vt = j % 5, h = j / 5;
    f32x4 acc[2] = {};
    for (int c = 0; c < NCHUNK; ++c) {
      unsigned short* dst = kvpre_pk + (size_t)(h * 32 + c) * 1280 * 8;
#pragma unroll
      for (int mb = 0; mb < 2; ++mb) {
        unsigned short vb[4];
#pragma unroll
        for (int r = 0; r < 4; ++r) vb[r] = f2bf(acc[mb][r]);
        const size_t u = (size_t)(vt * 4 + w) * 64 + r16 + (mb * 2 + (kg >> 1)) * 16;
        *(ushort4*)&dst[u * 8 + (kg & 1) * 4] = *(ushort4*)&vb[0];
      }
      const unsigned short* kb = kT_pk + (size_t)(h * 32 + c) * 1024 * 8;
      const unsigned short* vb_ = vT_pk + (size_t)(h * 32 + c) * 640 * 8;
#pragma unroll
      for (int s = 0; s < 2; ++s) {
        const bf16x8 bf = *(const bf16x8*)(vb_ + (((size_t)vt * 2 + s) * 64 + lane) * 8);
#pragma unroll
        for (int mb = 0; mb < 2; ++mb) {
          const bf16x8 af = *(const bf16x8*)(kb + ((((size_t)(w * 2 + mb)) * 2 + s) * 64 + lane) * 8);
          acc[mb] = __builtin_amdgcn_mfma_f32_16x16x32_bf16(af, bf, acc[mb], 0, 0, 0);
        }
      }
    }
  }
}

// ============ phase 3: chunk attention ============
// 256 jobs: c = j%32, h = j/32. Col 64 of combined accumulator = denominator.
__device__ void ph_attn(
    const unsigned short* q_pk, const unsigned short* k_pk,
    const unsigned short* kvpre_pk, const unsigned short* vT_pk,
    unsigned short* attn_pk)
{
  __shared__ unsigned short P[4096];   // PK(64,64), 8 KB
  __shared__ float den[64];
  const int lane = threadIdx.x & 63, w = threadIdx.x >> 6;
  const int wr = w >> 1, wc = w & 1;
  const int r16 = lane & 15, kg = lane >> 4;
  for (int j = blockIdx.x; j < 256; j += gridDim.x) {
    const int c = j % 32, h = j / 32;
    const unsigned short* qb = q_pk + (size_t)h * 262144;
    const unsigned short* kb = k_pk + (size_t)h * 262144;
    bf16x8 qa[2][4];
#pragma unroll
    for (int amb = 0; amb < 2; ++amb)
#pragma unroll
      for (int ks = 0; ks < 4; ++ks)
        qa[amb][ks] = *(const bf16x8*)(qb +
            (((size_t)(c * 4 + wr * 2 + amb) * 4 + ks) * 64 + lane) * 8);
    // Phase A: S = Q K^T, causal mask, P -> LDS
    {
      f32x4 accS[2][2] = {};
#pragma unroll
      for (int ks = 0; ks < 4; ++ks) {
#pragma unroll
        for (int bnb = 0; bnb < 2; ++bnb) {
          const bf16x8 bf = *(const bf16x8*)(kb +
              (((size_t)(c * 4 + wc * 2 + bnb) * 4 + ks) * 64 + lane) * 8);
#pragma unroll
          for (int amb = 0; amb < 2; ++amb)
            accS[amb][bnb] = __builtin_amdgcn_mfma_f32_16x16x32_bf16(qa[amb][ks], bf, accS[amb][bnb], 0, 0, 0);
        }
      }
#pragma unroll
      for (int amb = 0; amb < 2; ++amb)
#pragma unroll
        for (int bnb = 0; bnb < 2; ++bnb) {
          const int ck = wc * 32 + bnb * 16 + r16;
          const size_t u = ((size_t)(wr * 2 + amb) * 2 + wc) * 64 + (bnb * 2 + (r16 >> 3)) * 16;
          const int elem = r16 & 7;
#pragma unroll
          for (int r = 0; r < 4; ++r) {
            const int rq = wr * 32 + amb * 16 + kg * 4 + r;
            P[(u + kg * 4 + r) * 8 + elem] = (ck <= rq) ? f2bf(accS[amb][bnb][r]) : (unsigned short)0;
          }
        }
    }
    __syncthreads();
    // Phase B: O = Q @ KVpre'' + P @ V''
    const int nnt = wc ? 2 : 3;
    const int ntb = wc ? 3 : 0;
    const unsigned short* kvp = kvpre_pk + (size_t)(h * 32 + c) * 1280 * 8;
    const unsigned short* vtb = vT_pk + (size_t)(h * 32 + c) * 640 * 8;
    f32x4 acc[2][3] = {};
#pragma unroll
    for (int ks = 0; ks < 4; ++ks) {
      bf16x8 bfr[3];
      for (int jj = 0; jj < 3; ++jj)
        if (jj < nnt)
          bfr[jj] = *(const bf16x8*)(kvp + (((size_t)(ntb + jj) * 4 + ks) * 64 + lane) * 8);
#pragma unroll
      for (int amb = 0; amb < 2; ++amb)
        for (int jj = 0; jj < 3; ++jj)
          if (jj < nnt)
            acc[amb][jj] = __builtin_amdgcn_mfma_f32_16x16x32_bf16(qa[amb][ks], bfr[jj], acc[amb][jj], 0, 0, 0);
    }
#pragma unroll
    for (int ks = 0; ks < 2; ++ks) {
      bf16x8 bfr[3];
      for (int jj = 0; jj < 3; ++jj)
        if (jj < nnt)
          bfr[jj] = *(const bf16x8*)(vtb + (((size_t)(ntb + jj) * 2 + ks) * 64 + lane) * 8);
#pragma unroll
      for (int amb = 0; amb < 2; ++amb) {
        const bf16x8 pf = *(const bf16x8*)&P[((((size_t)(wr * 2 + amb)) * 2 + ks) * 64 + lane) * 8];
        for (int jj = 0; jj < 3; ++jj)
          if (jj < nnt)
            acc[amb][jj] = __builtin_amdgcn_mfma_f32_16x16x32_bf16(pf, bfr[jj], acc[amb][jj], 0, 0, 0);
      }
    }
    if (wc == 1 && r16 == 0) {
#pragma unroll
      for (int amb = 0; amb < 2; ++amb)
#pragma unroll
        for (int r = 0; r < 4; ++r)
          den[wr * 32 + amb * 16 + kg * 4 + r] = acc[amb][1][r] + EPS_C;
    }
    __syncthreads();
#pragma unroll
    for (int amb = 0; amb < 2; ++amb) {
      for (int jj = 0; jj < 3; ++jj) {
        const int nt = ntb + jj;
        if (nt >= 4 || jj >= nnt) continue;
        const int acol = h * 64 + nt * 16 + r16;
        const size_t base = ((size_t)(c * 4 + wr * 2 + amb) * 16 + (acol >> 5)) * 64 +
                            ((nt * 2 + (r16 >> 3)) & 3) * 16;
        const int elem = acol & 7;
#pragma unroll
        for (int r = 0; r < 4; ++r) {
          const float dinv = 1.0f / den[wr * 32 + amb * 16 + kg * 4 + r];
          attn_pk[(base + kg * 4 + r) * 8 + elem] = f2bf(acc[amb][jj][r] * dinv);
        }
      }
    }
    __syncthreads();   // protect P/den LDS reuse by next iteration
  }
}

// ============ phase 4: out = attn @ W_out + b_out ============
// 256 jobs: nx = j%8 col tile, my = j/8 row tile. K=512.
__device__ void ph_out(
    const unsigned short* Apk, const unsigned short* Bpk,
    const float* bias, float* Cf)
{
  const int lane = threadIdx.x & 63, w = threadIdx.x >> 6;
  const int wr = w >> 1, wc = w & 1;
  const int r16 = lane & 15, kg = lane >> 4;
  for (int j = blockIdx.x; j < 256; j += gridDim.x) {
    const int nx = j % 8, my = j / 8;
    const int m0 = my * 64 + wr * 32;
    const int n0 = nx * 64 + wc * 32;
    const unsigned short* a0 = Apk + ((size_t)(m0 >> 4) * 16 * 64 + lane) * 8;
    const unsigned short* a1 = a0 + (size_t)16 * 512;
    const unsigned short* b0 = Bpk + ((size_t)(n0 >> 4) * 16 * 64 + lane) * 8;
    const unsigned short* b1 = b0 + (size_t)16 * 512;
    f32x4 acc00 = {0.f, 0.f, 0.f, 0.f}, acc01 = acc00, acc10 = acc00, acc11 = acc00;
#pragma unroll 4
    for (int s = 0; s < 16; ++s) {
      const bf16x8 af0 = *(const bf16x8*)(a0 + (size_t)s * 512);
      const bf16x8 af1 = *(const bf16x8*)(a1 + (size_t)s * 512);
      const bf16x8 bv0 = *(const bf16x8*)(b0 + (size_t)s * 512);
      const bf16x8 bv1 = *(const bf16x8*)(b1 + (size_t)s * 512);
      acc00 = __builtin_amdgcn_mfma_f32_16x16x32_bf16(af0, bv0, acc00, 0, 0, 0);
      acc01 = __builtin_amdgcn_mfma_f32_16x16x32_bf16(af0, bv1, acc01, 0, 0, 0);
      acc10 = __builtin_amdgcn_mfma_f32_16x16x32_bf16(af1, bv0, acc10, 0, 0, 0);
      acc11 = __builtin_amdgcn_mfma_f32_16x16x32_bf16(af1, bv1, acc11, 0, 0, 0);
    }
#pragma unroll
    for (int mb = 0; mb < 2; ++mb) {
#pragma unroll
      for (int nb = 0; nb < 2; ++nb) {
        const f32x4 a = mb == 0 ? (nb == 0 ? acc00 : acc01) : (nb == 0 ? acc10 : acc11);
        const int col = n0 + nb * 16 + r16;
        const float bv = bias[col];
#pragma unroll
        for (int r = 0; r < 4; ++r)
          Cf[(size_t)(m0 + mb * 16 + kg * 4 + r) * 512 + col] = a[r] + bv;
      }
    }
  }
}

// ============ cooperative megakernel ============
__global__ __launch_bounds__(256) void mega(
    const float* x, const float* proj, const float* W_qkv, const float* W_out,
    const float* b_out, float* out,
    unsigned short* xpk, unsigned short* wqkvpk, unsigned short* woutpk,
    unsigned short* projpk, unsigned short* q_pk, unsigned short* k_pk,
    unsigned short* kT_pk, unsigned short* vT_pk, unsigned short* kvpre_pk,
    unsigned short* attn_pk)
{
  cg::grid_group g = cg::this_grid();
  ph_pack(x, W_qkv, W_out, proj, xpk, wqkvpk, woutpk, projpk, vT_pk);
  g.sync();
  ph_qkvproj(xpk, wqkvpk, projpk, q_pk, k_pk, kT_pk, vT_pk);
  g.sync();
  ph_scan(kT_pk, vT_pk, kvpre_pk);
  g.sync();
  ph_attn(q_pk, k_pk, kvpre_pk, vT_pk, attn_pk);
  g.sync();
  ph_out(attn_pk, woutpk, b_out, out);
}

// ============ fallback wrappers (same device code, 5 launches) ============
__global__ __launch_bounds__(256) void k_pack(
    const float* x, const float* W_qkv, const float* W_out, const float* proj,
    unsigned short* xpk, unsigned short* wqkvpk, unsigned short* woutpk,
    unsigned short* projpk, unsigned short* vT_pk)
{ ph_pack(x, W_qkv, W_out, proj, xpk, wqkvpk, woutpk, projpk, vT_pk); }

__global__ __launch_bounds__(256) void k_qkvproj(
    const unsigned short* Apk, const unsigned short* Bpk,
    const unsigned short* projpk, unsigned short* q_pk, unsigned short* k_pk,
    unsigned short* kT_pk, unsigned short* vT_pk)
{ ph_qkvproj(Apk, Bpk, projpk, q_pk, k_pk, kT_pk, vT_pk); }

__global__ __launch_bounds__(256) void k_scan(
    const unsigned short* kT_pk, const unsigned short* vT_pk,
    unsigned short* kvpre_pk)
{ ph_scan(kT_pk, vT_pk, kvpre_pk); }

__global__ __launch_bounds__(256) void k_attn(
    const unsigned short* q_pk, const unsigned short* k_pk,
    const unsigned short* kvpre_pk, const unsigned short* vT_pk,
    unsigned short* attn_pk)
{ ph_attn(q_pk, k_pk, kvpre_pk, vT_pk, attn_pk); }

__global__ __launch_bounds__(256) void k_out(
    const unsigned short* Apk, const unsigned short* Bpk,
    const float* bias, float* Cf)
{ ph_out(Apk, Bpk, bias, Cf); }

extern "C" void kernel_launch(void* const* d_in, const int* in_sizes, int n_in,
                              void* d_out, int out_size, void* d_ws, size_t ws_size,
                              hipStream_t stream) {
  const float* x     = (const float*)d_in[0];
  const float* proj  = (const float*)d_in[1];
  const float* W_qkv = (const float*)d_in[2];
  const float* W_out = (const float*)d_in[3];
  const float* b_out = (const float*)d_in[4];
  float* out = (float*)d_out;

  unsigned short* xpk      = (unsigned short*)d_ws;          // 1,048,576 us
  unsigned short* wqkvpk   = xpk + 1048576;                  //   786,432
  unsigned short* woutpk   = wqkvpk + 786432;                //   262,144
  unsigned short* projpk   = woutpk + 262144;                //    65,536
  unsigned short* q_pk     = projpk + 65536;                 // 2,097,152
  unsigned short* k_pk     = q_pk + 2097152;                 // 2,097,152
  unsigned short* kT_pk    = k_pk + 2097152;                 // 2,097,152
  unsigned short* vT_pk    = kT_pk + 2097152;                // 1,310,720
  unsigned short* kvpre_pk = vT_pk + 1310720;                // 2,621,440
  unsigned short* attn_pk  = kvpre_pk + 2621440;             // 1,048,576
  // total 13,434,880 ushorts ~ 26.9 MB

  int occ = 0;
  (void)hipOccupancyMaxActiveBlocksPerMultiprocessor(&occ, (const void*)mega, 256, 0);
  if (occ < 1) occ = 1;
  if (occ > 3) occ = 3;               // 768 jobs max in any phase
  const int nblk = 256 * occ;

  void* args[] = {
    (void*)&x, (void*)&proj, (void*)&W_qkv, (void*)&W_out, (void*)&b_out,
    (void*)&out, (void*)&xpk, (void*)&wqkvpk, (void*)&woutpk, (void*)&projpk,
    (void*)&q_pk, (void*)&k_pk, (void*)&kT_pk, (void*)&vT_pk, (void*)&kvpre_pk,
    (void*)&attn_pk };
  const hipError_t le = hipLaunchCooperativeKernel(
      (const void*)mega, dim3(nblk), dim3(256), args, 0, stream);
  if (le != hipSuccess) {
    // fallback: identical math, 5 launches (round-6 behavior)
    k_pack<<<1184, 256, 0, stream>>>(x, W_qkv, W_out, proj,
                                     xpk, wqkvpk, woutpk, projpk, vT_pk);
    k_qkvproj<<<768, 256, 0, stream>>>(xpk, wqkvpk, projpk, q_pk, k_pk, kT_pk, vT_pk);
    k_scan<<<40, 256, 0, stream>>>(kT_pk, vT_pk, kvpre_pk);
    k_attn<<<256, 256, 0, stream>>>(q_pk, k_pk, kvpre_pk, vT_pk, attn_pk);
    k_out<<<256, 256, 0, stream>>>(attn_pk, woutpk, b_out, out);
  }
}

// Round 8
// 53.186 us; speedup vs baseline: 3.6649x; 3.6649x over previous
//
#include <hip/hip_runtime.h>
#include <math.h>

#define NTOK 2048
#define DMODEL 512
#define NH 8
#define HD 64
#define NF 128
#define QKV_LD 1536
#define CHUNK 64
#define NCHUNK 32
#define EPS_C 1e-8f

typedef __bf16 bf16x8 __attribute__((ext_vector_type(8)));
typedef float f32x4 __attribute__((ext_vector_type(4)));

__device__ inline unsigned short f2bf(float f) {
  union { float f; unsigned u; } v; v.f = f;
  unsigned r = v.u + 0x7FFF + ((v.u >> 16) & 1);   // RNE
  return (unsigned short)(r >> 16);
}

// Packed fragment layout PK(M,K) for MFMA operand (A: [m][k]; B: [n][k]):
//   unit(m,k)  = ((m>>4)*(K>>5) + (k>>5))*64 + (m&15) + ((k>>3)&3)*16
//   ushort idx = unit*8 + (k&7)

// ============ pack: inputs -> packed bf16 (+ V'' ones tile) ============
// exact flat grid of 1184 blocks:
// [0,512) x | [512,896) W_qkv | [896,1024) W_out | [1024,1056) proj | [1056,1184) vT ones
__global__ __launch_bounds__(256) void pack_flat(
    const float* __restrict__ x, const float* __restrict__ W_qkv,
    const float* __restrict__ W_out, const float* __restrict__ proj,
    unsigned short* __restrict__ xpk, unsigned short* __restrict__ wqkvpk,
    unsigned short* __restrict__ woutpk, unsigned short* __restrict__ projpk,
    unsigned short* __restrict__ vT_pk)
{
  const int v = blockIdx.x;
  unsigned short o[8];
  if (v < 512) {
    const int tid = v * 256 + threadIdx.x;            // < 131072
    const int lane = tid & 63, blk = tid >> 6;
    const int bk = blk & 15, bm = blk >> 4;
    const int m = bm * 16 + (lane & 15), k = bk * 32 + (lane >> 4) * 8;
    const float4 v0 = *(const float4*)&x[(size_t)m * 512 + k];
    const float4 v1 = *(const float4*)&x[(size_t)m * 512 + k + 4];
    o[0] = f2bf(v0.x); o[1] = f2bf(v0.y); o[2] = f2bf(v0.z); o[3] = f2bf(v0.w);
    o[4] = f2bf(v1.x); o[5] = f2bf(v1.y); o[6] = f2bf(v1.z); o[7] = f2bf(v1.w);
    *(ushort4*)&xpk[(size_t)tid * 8]     = *(ushort4*)&o[0];
    *(ushort4*)&xpk[(size_t)tid * 8 + 4] = *(ushort4*)&o[4];
  } else if (v < 896) {
    const int tid = (v - 512) * 256 + threadIdx.x;    // < 98304
    const int lane = tid & 63, blk = tid >> 6;
    const int bk = blk & 15, bn = blk >> 4;
    const int n = bn * 16 + (lane & 15), k = bk * 32 + (lane >> 4) * 8;
#pragma unroll
    for (int e = 0; e < 8; ++e) o[e] = f2bf(W_qkv[(size_t)(k + e) * QKV_LD + n]);
    *(ushort4*)&wqkvpk[(size_t)tid * 8]     = *(ushort4*)&o[0];
    *(ushort4*)&wqkvpk[(size_t)tid * 8 + 4] = *(ushort4*)&o[4];
  } else if (v < 1024) {
    const int tid = (v - 896) * 256 + threadIdx.x;    // < 32768
    const int lane = tid & 63, blk = tid >> 6;
    const int bk = blk & 15, bn = blk >> 4;
    const int n = bn * 16 + (lane & 15), k = bk * 32 + (lane >> 4) * 8;
#pragma unroll
    for (int e = 0; e < 8; ++e) o[e] = f2bf(W_out[(size_t)(k + e) * DMODEL + n]);
    *(ushort4*)&woutpk[(size_t)tid * 8]     = *(ushort4*)&o[0];
    *(ushort4*)&woutpk[(size_t)tid * 8 + 4] = *(ushort4*)&o[4];
  } else if (v < 1056) {
    const int tid = (v - 1024) * 256 + threadIdx.x;   // < 8192
    const int lane = tid & 63, blk = (tid >> 6) & 15, h = tid >> 10;
    const int bk = blk & 1, bn = blk >> 1;
    const int n = bn * 16 + (lane & 15), k = bk * 32 + (lane >> 4) * 8;
#pragma unroll
    for (int e = 0; e < 8; ++e) o[e] = f2bf(proj[(size_t)h * HD * NF + (size_t)(k + e) * NF + n]);
    *(ushort4*)&projpk[(size_t)tid * 8]     = *(ushort4*)&o[0];
    *(ushort4*)&projpk[(size_t)tid * 8 + 4] = *(ushort4*)&o[4];
  } else {
    const int tid = (v - 1056) * 256 + threadIdx.x;   // < 32768
    const int hc = tid >> 7, kt = (tid >> 6) & 1, lane = tid & 63;
    const unsigned short val = ((lane & 15) == 0) ? (unsigned short)0x3F80 : (unsigned short)0;
    const size_t u = (size_t)hc * 640 + (4 * 2 + kt) * 64 + lane;
#pragma unroll
    for (int e = 0; e < 8; ++e) o[e] = val;
    *(ushort4*)&vT_pk[u * 8]     = *(ushort4*)&o[0];
    *(ushort4*)&vT_pk[u * 8 + 4] = *(ushort4*)&o[4];
  }
}

// ============ fused qkv GEMM + proj + elu+1 ============
// grid (24, 32): blockIdx.x = 64-col tile (0-7 Q, 8-15 K, 16-23 V), y = chunk.
__global__ __launch_bounds__(256) void qkv_proj(
    const unsigned short* __restrict__ Apk, const unsigned short* __restrict__ Bpk,
    const unsigned short* __restrict__ projpk,
    unsigned short* __restrict__ q_pk, unsigned short* __restrict__ k_pk,
    unsigned short* __restrict__ kT_pk, unsigned short* __restrict__ vT_pk)
{
  __shared__ unsigned short QK[4096];   // PK(64,64), 8 KB
  const int lane = threadIdx.x & 63, w = threadIdx.x >> 6;
  const int wr = w >> 1, wc = w & 1;
  const int c = blockIdx.y;
  const int m0 = c * 64 + wr * 32;
  const int n0 = blockIdx.x * 64 + wc * 32;
  const unsigned short* a0 = Apk + ((size_t)(m0 >> 4) * 16 * 64 + lane) * 8;
  const unsigned short* a1 = a0 + (size_t)16 * 512;
  const unsigned short* b0 = Bpk + ((size_t)(n0 >> 4) * 16 * 64 + lane) * 8;
  const unsigned short* b1 = b0 + (size_t)16 * 512;
  f32x4 acc00 = {0.f, 0.f, 0.f, 0.f}, acc01 = acc00, acc10 = acc00, acc11 = acc00;
#pragma unroll 8
  for (int s = 0; s < 16; ++s) {
    const bf16x8 af0 = *(const bf16x8*)(a0 + (size_t)s * 512);
    const bf16x8 af1 = *(const bf16x8*)(a1 + (size_t)s * 512);
    const bf16x8 bv0 = *(const bf16x8*)(b0 + (size_t)s * 512);
    const bf16x8 bv1 = *(const bf16x8*)(b1 + (size_t)s * 512);
    acc00 = __builtin_amdgcn_mfma_f32_16x16x32_bf16(af0, bv0, acc00, 0, 0, 0);
    acc01 = __builtin_amdgcn_mfma_f32_16x16x32_bf16(af0, bv1, acc01, 0, 0, 0);
    acc10 = __builtin_amdgcn_mfma_f32_16x16x32_bf16(af1, bv0, acc10, 0, 0, 0);
    acc11 = __builtin_amdgcn_mfma_f32_16x16x32_bf16(af1, bv1, acc11, 0, 0, 0);
  }
  const int r16 = lane & 15, kg = lane >> 4;
  if (blockIdx.x < 16) {
    const int src = blockIdx.x >> 3, h = blockIdx.x & 7;
    // qkv tile -> LDS PK(64,64)
#pragma unroll
    for (int mb = 0; mb < 2; ++mb) {
#pragma unroll
      for (int nb = 0; nb < 2; ++nb) {
        const f32x4 a = mb == 0 ? (nb == 0 ? acc00 : acc01) : (nb == 0 ? acc10 : acc11);
        const size_t u = ((size_t)(wr * 2 + mb) * 2 + wc) * 64 +
                         (nb * 2 + (r16 >> 3)) * 16 + kg * 4;
        const int elem = r16 & 7;
#pragma unroll
        for (int r = 0; r < 4; ++r)
          QK[(u + r) * 8 + elem] = f2bf(a[r]);
      }
    }
    __syncthreads();
    // proj GEMM 64x128xK=64 + elu+1
    const unsigned short* bbase = projpk + (size_t)h * 8192 + (size_t)lane * 8;
    f32x4 p[2][4] = {};
#pragma unroll
    for (int s = 0; s < 2; ++s) {
#pragma unroll
      for (int mb = 0; mb < 2; ++mb) {
        const bf16x8 af = *(const bf16x8*)&QK[((((size_t)(wr * 2 + mb)) * 2 + s) * 64 + lane) * 8];
#pragma unroll
        for (int nb = 0; nb < 4; ++nb) {
          const bf16x8 bv = *(const bf16x8*)(bbase + (size_t)((wc * 4 + nb) * 2 + s) * 512);
          p[mb][nb] = __builtin_amdgcn_mfma_f32_16x16x32_bf16(af, bv, p[mb][nb], 0, 0, 0);
        }
      }
    }
    unsigned short* dst = (src ? k_pk : q_pk) + (size_t)h * 262144;
#pragma unroll
    for (int mb = 0; mb < 2; ++mb) {
#pragma unroll
      for (int nb = 0; nb < 4; ++nb) {
        unsigned short vb[4];
#pragma unroll
        for (int r = 0; r < 4; ++r) {
          const float vv = p[mb][nb][r];
          vb[r] = f2bf(vv > 0.f ? vv + 1.f : expf(vv));
        }
        const size_t base = ((size_t)(c * 4 + wr * 2 + mb) * 4 + wc * 2 + (nb >> 1)) * 64 +
                            ((nb & 1) * 2 + (r16 >> 3)) * 16;
        const int elem = r16 & 7;
#pragma unroll
        for (int r = 0; r < 4; ++r)
          dst[(base + kg * 4 + r) * 8 + elem] = vb[r];
        if (src == 1) {
          const size_t u = (size_t)(h * 32 + c) * 1024 +
              ((size_t)(wc * 4 + nb) * 2 + wr) * 64 + r16 + (mb * 2 + (kg >> 1)) * 16;
          *(ushort4*)&kT_pk[u * 8 + (kg & 1) * 4] = *(ushort4*)&vb[0];
        }
      }
    }
  } else {
    // V -> vT_pk PK(80,64) per (h,c), transposed
    const int h = blockIdx.x - 16;
#pragma unroll
    for (int mb = 0; mb < 2; ++mb) {
#pragma unroll
      for (int nb = 0; nb < 2; ++nb) {
        const f32x4 a = mb == 0 ? (nb == 0 ? acc00 : acc01) : (nb == 0 ? acc10 : acc11);
        const int vc = wc * 32 + nb * 16 + r16;
        const size_t u = (size_t)(h * 32 + c) * 640 +
            ((size_t)(vc >> 4) * 2 + wr) * 64 + (vc & 15) + (mb * 2 + (kg >> 1)) * 16;
        ushort4 rr;
        rr.x = f2bf(a[0]); rr.y = f2bf(a[1]); rr.z = f2bf(a[2]); rr.w = f2bf(a[3]);
        *(ushort4*)&vT_pk[u * 8 + (kg & 1) * 4] = rr;
      }
    }
  }
}

// ============ fused chunk-sums + exclusive scan ============
// grid (5 vtiles, NH), 4 waves; MFMA accumulator IS the running prefix.
__global__ __launch_bounds__(256) void sums_scan(
    const unsigned short* __restrict__ kT_pk, const unsigned short* __restrict__ vT_pk,
    unsigned short* __restrict__ kvpre_pk)
{
  const int lane = threadIdx.x & 63, w = threadIdx.x >> 6;
  const int vt = blockIdx.x, h = blockIdx.y;
  const int r16 = lane & 15, kg = lane >> 4;
  f32x4 acc[2] = {};
  for (int c = 0; c < NCHUNK; ++c) {
    unsigned short* dst = kvpre_pk + (size_t)(h * 32 + c) * 1280 * 8;
#pragma unroll
    for (int mb = 0; mb < 2; ++mb) {
      unsigned short vb[4];
#pragma unroll
      for (int r = 0; r < 4; ++r) vb[r] = f2bf(acc[mb][r]);
      const size_t u = (size_t)(vt * 4 + w) * 64 + r16 + (mb * 2 + (kg >> 1)) * 16;
      *(ushort4*)&dst[u * 8 + (kg & 1) * 4] = *(ushort4*)&vb[0];
    }
    const unsigned short* kb = kT_pk + (size_t)(h * 32 + c) * 1024 * 8;
    const unsigned short* vb_ = vT_pk + (size_t)(h * 32 + c) * 640 * 8;
#pragma unroll
    for (int s = 0; s < 2; ++s) {
      const bf16x8 bf = *(const bf16x8*)(vb_ + (((size_t)vt * 2 + s) * 64 + lane) * 8);
#pragma unroll
      for (int mb = 0; mb < 2; ++mb) {
        const bf16x8 af = *(const bf16x8*)(kb + ((((size_t)(w * 2 + mb)) * 2 + s) * 64 + lane) * 8);
        acc[mb] = __builtin_amdgcn_mfma_f32_16x16x32_bf16(af, bf, acc[mb], 0, 0, 0);
      }
    }
  }
}

// ============ chunk attention, 2-wave half-blocks ============
// grid (NCHUNK, NH, 2): z = 32-row half. 128 threads = 2 waves (wc col halves).
// Col 64 of the combined accumulator IS the denominator.
__global__ __launch_bounds__(128) void chunk_attn2(
    const unsigned short* __restrict__ q_pk, const unsigned short* __restrict__ k_pk,
    const unsigned short* __restrict__ kvpre_pk, const unsigned short* __restrict__ vT_pk,
    unsigned short* __restrict__ attn_pk)
{
  __shared__ unsigned short P[2048];   // PK(32,64) = 256 units, 4 KB
  __shared__ float den[32];
  const int lane = threadIdx.x & 63, wc = threadIdx.x >> 6;
  const int c = blockIdx.x, h = blockIdx.y, rh = blockIdx.z;
  const int r16 = lane & 15, kg = lane >> 4;
  const unsigned short* qb = q_pk + (size_t)h * 262144;
  const unsigned short* kb = k_pk + (size_t)h * 262144;
  bf16x8 qa[2][4];
#pragma unroll
  for (int amb = 0; amb < 2; ++amb)
#pragma unroll
    for (int ks = 0; ks < 4; ++ks)
      qa[amb][ks] = *(const bf16x8*)(qb +
          (((size_t)(c * 4 + rh * 2 + amb) * 4 + ks) * 64 + lane) * 8);
  // Phase A: S = Q K^T (own 32 rows x wc's 32 cols), causal mask, P -> LDS
  {
    f32x4 accS[2][2] = {};
#pragma unroll
    for (int ks = 0; ks < 4; ++ks) {
#pragma unroll
      for (int bnb = 0; bnb < 2; ++bnb) {
        const bf16x8 bf = *(const bf16x8*)(kb +
            (((size_t)(c * 4 + wc * 2 + bnb) * 4 + ks) * 64 + lane) * 8);
#pragma unroll
        for (int amb = 0; amb < 2; ++amb)
          accS[amb][bnb] = __builtin_amdgcn_mfma_f32_16x16x32_bf16(qa[amb][ks], bf, accS[amb][bnb], 0, 0, 0);
      }
    }
#pragma unroll
    for (int amb = 0; amb < 2; ++amb)
#pragma unroll
      for (int bnb = 0; bnb < 2; ++bnb) {
        const int ck = wc * 32 + bnb * 16 + r16;
        const size_t u = ((size_t)amb * 2 + wc) * 64 + (bnb * 2 + (r16 >> 3)) * 16;
        const int elem = r16 & 7;
#pragma unroll
        for (int r = 0; r < 4; ++r) {
          const int rq = rh * 32 + amb * 16 + kg * 4 + r;
          P[(u + kg * 4 + r) * 8 + elem] = (ck <= rq) ? f2bf(accS[amb][bnb][r]) : (unsigned short)0;
        }
      }
  }
  __syncthreads();
  // Phase B: O = Q @ KVpre'' + P @ V''
  const int nnt = wc ? 2 : 3;
  const int ntb = wc ? 3 : 0;
  const unsigned short* kvp = kvpre_pk + (size_t)(h * 32 + c) * 1280 * 8;
  const unsigned short* vtb = vT_pk + (size_t)(h * 32 + c) * 640 * 8;
  f32x4 acc[2][3] = {};
#pragma unroll
  for (int ks = 0; ks < 4; ++ks) {
    bf16x8 bfr[3];
    for (int jj = 0; jj < 3; ++jj)
      if (jj < nnt)
        bfr[jj] = *(const bf16x8*)(kvp + (((size_t)(ntb + jj) * 4 + ks) * 64 + lane) * 8);
#pragma unroll
    for (int amb = 0; amb < 2; ++amb)
      for (int jj = 0; jj < 3; ++jj)
        if (jj < nnt)
          acc[amb][jj] = __builtin_amdgcn_mfma_f32_16x16x32_bf16(qa[amb][ks], bfr[jj], acc[amb][jj], 0, 0, 0);
  }
#pragma unroll
  for (int ks = 0; ks < 2; ++ks) {
    bf16x8 bfr[3];
    for (int jj = 0; jj < 3; ++jj)
      if (jj < nnt)
        bfr[jj] = *(const bf16x8*)(vtb + (((size_t)(ntb + jj) * 2 + ks) * 64 + lane) * 8);
#pragma unroll
    for (int amb = 0; amb < 2; ++amb) {
      const bf16x8 pf = *(const bf16x8*)&P[(((size_t)amb * 2 + ks) * 64 + lane) * 8];
      for (int jj = 0; jj < 3; ++jj)
        if (jj < nnt)
          acc[amb][jj] = __builtin_amdgcn_mfma_f32_16x16x32_bf16(pf, bfr[jj], acc[amb][jj], 0, 0, 0);
    }
  }
  if (wc == 1 && r16 == 0) {
#pragma unroll
    for (int amb = 0; amb < 2; ++amb)
#pragma unroll
      for (int r = 0; r < 4; ++r)
        den[amb * 16 + kg * 4 + r] = acc[amb][1][r] + EPS_C;
  }
  __syncthreads();
#pragma unroll
  for (int amb = 0; amb < 2; ++amb) {
    for (int jj = 0; jj < 3; ++jj) {
      const int nt = ntb + jj;
      if (nt >= 4 || jj >= nnt) continue;
      const int acol = h * 64 + nt * 16 + r16;
      const size_t base = ((size_t)(c * 4 + rh * 2 + amb) * 16 + (acol >> 5)) * 64 +
                          ((nt * 2 + (r16 >> 3)) & 3) * 16;
      const int elem = acol & 7;
#pragma unroll
      for (int r = 0; r < 4; ++r) {
        const float dinv = 1.0f / den[amb * 16 + kg * 4 + r];
        attn_pk[(base + kg * 4 + r) * 8 + elem] = f2bf(acc[amb][jj][r] * dinv);
      }
    }
  }
}

// ============ out = attn @ W_out + b_out ============
__global__ __launch_bounds__(256) void gemm_out(
    const unsigned short* __restrict__ Apk, const unsigned short* __restrict__ Bpk,
    const float* __restrict__ bias, float* __restrict__ Cf, int K, int ldc)
{
  const int lane = threadIdx.x & 63, w = threadIdx.x >> 6;
  const int wr = w >> 1, wc = w & 1;
  const int m0 = blockIdx.y * 64 + wr * 32;
  const int n0 = blockIdx.x * 64 + wc * 32;
  const int ks = K >> 5;
  const unsigned short* a0 = Apk + ((size_t)(m0 >> 4) * ks * 64 + lane) * 8;
  const unsigned short* a1 = a0 + (size_t)ks * 512;
  const unsigned short* b0 = Bpk + ((size_t)(n0 >> 4) * ks * 64 + lane) * 8;
  const unsigned short* b1 = b0 + (size_t)ks * 512;
  f32x4 acc00 = {0.f, 0.f, 0.f, 0.f}, acc01 = acc00, acc10 = acc00, acc11 = acc00;
#pragma unroll 8
  for (int s = 0; s < ks; ++s) {
    const bf16x8 af0 = *(const bf16x8*)(a0 + (size_t)s * 512);
    const bf16x8 af1 = *(const bf16x8*)(a1 + (size_t)s * 512);
    const bf16x8 bv0 = *(const bf16x8*)(b0 + (size_t)s * 512);
    const bf16x8 bv1 = *(const bf16x8*)(b1 + (size_t)s * 512);
    acc00 = __builtin_amdgcn_mfma_f32_16x16x32_bf16(af0, bv0, acc00, 0, 0, 0);
    acc01 = __builtin_amdgcn_mfma_f32_16x16x32_bf16(af0, bv1, acc01, 0, 0, 0);
    acc10 = __builtin_amdgcn_mfma_f32_16x16x32_bf16(af1, bv0, acc10, 0, 0, 0);
    acc11 = __builtin_amdgcn_mfma_f32_16x16x32_bf16(af1, bv1, acc11, 0, 0, 0);
  }
  const int r16 = lane & 15, kg = lane >> 4;
#pragma unroll
  for (int mb = 0; mb < 2; ++mb) {
#pragma unroll
    for (int nb = 0; nb < 2; ++nb) {
      const f32x4 a = mb == 0 ? (nb == 0 ? acc00 : acc01) : (nb == 0 ? acc10 : acc11);
      const int col = n0 + nb * 16 + r16;
      const float bv = bias[col];
#pragma unroll
      for (int r = 0; r < 4; ++r)
        Cf[(size_t)(m0 + mb * 16 + kg * 4 + r) * ldc + col] = a[r] + bv;
    }
  }
}

extern "C" void kernel_launch(void* const* d_in, const int* in_sizes, int n_in,
                              void* d_out, int out_size, void* d_ws, size_t ws_size,
                              hipStream_t stream) {
  const float* x     = (const float*)d_in[0];
  const float* proj  = (const float*)d_in[1];
  const float* W_qkv = (const float*)d_in[2];
  const float* W_out = (const float*)d_in[3];
  const float* b_out = (const float*)d_in[4];
  float* out = (float*)d_out;

  unsigned short* xpk      = (unsigned short*)d_ws;          // 1,048,576 us
  unsigned short* wqkvpk   = xpk + 1048576;                  //   786,432
  unsigned short* woutpk   = wqkvpk + 786432;                //   262,144
  unsigned short* projpk   = woutpk + 262144;                //    65,536
  unsigned short* q_pk     = projpk + 65536;                 // 2,097,152
  unsigned short* k_pk     = q_pk + 2097152;                 // 2,097,152
  unsigned short* kT_pk    = k_pk + 2097152;                 // 2,097,152
  unsigned short* vT_pk    = kT_pk + 2097152;                // 1,310,720
  unsigned short* kvpre_pk = vT_pk + 1310720;                // 2,621,440
  unsigned short* attn_pk  = kvpre_pk + 2621440;             // 1,048,576
  // total 13,434,880 ushorts ~ 26.9 MB

  // 0) pack inputs + constant V'' ones-tile (exact 1184-block flat grid)
  pack_flat<<<dim3(1184), 256, 0, stream>>>(x, W_qkv, W_out, proj,
                                            xpk, wqkvpk, woutpk, projpk, vT_pk);
  // 1) fused qkv GEMM + proj + elu -> q_pk, k_pk, kT_pk, vT_pk
  qkv_proj<<<dim3(QKV_LD / 64, NTOK / 64), 256, 0, stream>>>(
      xpk, wqkvpk, projpk, q_pk, k_pk, kT_pk, vT_pk);
  // 2) fused chunk-sums + exclusive prefix -> kvpre_pk (col 64 = kpre)
  sums_scan<<<dim3(5, NH), 256, 0, stream>>>(kT_pk, vT_pk, kvpre_pk);
  // 3) chunk attention (2-wave half-blocks) -> attn_pk
  chunk_attn2<<<dim3(NCHUNK, NH, 2), 128, 0, stream>>>(
      q_pk, k_pk, kvpre_pk, vT_pk, attn_pk);
  // 4) out = attn @ W_out + b_out
  gemm_out<<<dim3(DMODEL / 64, NTOK / 64), 256, 0, stream>>>(
      attn_pk, woutpk, b_out, out, DMODEL, DMODEL);
}